// Round 9
// baseline (231.993 us; speedup 1.0000x reference)
//
#include <hip/hip_runtime.h>
#include <math.h>

#define T_TOTAL 16384
#define HDIM    2048
#define NEXP    64

typedef unsigned short ushort_t;
using bf16x8 = __attribute__((ext_vector_type(8))) short;
using f32x4  = __attribute__((ext_vector_type(4))) float;

// ---------------------------------------------------------------------------
// fp32 -> bf16 split: x = hi + mid + lo, residuals exact in fp32. 8-term
// contraction -> dropped error ~2^-36 |x||w| (r8-proven numerics).
// ---------------------------------------------------------------------------
__device__ __forceinline__ unsigned cvtpk_bf16(float a, float b) {
    unsigned r;
    asm("v_cvt_pk_bf16_f32 %0, %1, %2" : "=v"(r) : "v"(a), "v"(b));
    return r;
}

__device__ __forceinline__ void split8(const float4 a, const float4 b,
                                       bf16x8& h, bf16x8& m, bf16x8& l) {
    const float f[8] = {a.x, a.y, a.z, a.w, b.x, b.y, b.z, b.w};
    union { unsigned u[4]; bf16x8 v; } H, M, L;
#pragma unroll
    for (int d = 0; d < 4; ++d) {
        const float f0 = f[2*d], f1 = f[2*d+1];
        const unsigned ph = cvtpk_bf16(f0, f1);
        const float r0 = f0 - __uint_as_float(ph << 16);
        const float r1 = f1 - __uint_as_float(ph & 0xFFFF0000u);
        const unsigned pm = cvtpk_bf16(r0, r1);
        const float s0 = r0 - __uint_as_float(pm << 16);
        const float s1 = r1 - __uint_as_float(pm & 0xFFFF0000u);
        H.u[d] = ph;
        M.u[d] = pm;
        L.u[d] = cvtpk_bf16(s0, s1);
    }
    h = H.v; m = M.v; l = L.v;
}

// async global->LDS, 16B per lane: src PER-LANE, dst = uniform base + 16*lane
__device__ __forceinline__ void load_lds16(const void* g, void* lds) {
    __builtin_amdgcn_global_load_lds(
        (const __attribute__((address_space(1))) unsigned int*)g,
        (__attribute__((address_space(3))) unsigned int*)lds, 16, 0, 0);
}

// X staging swizzle: bijective on 16 chunks, same function on write & read
__device__ __forceinline__ int xswz(int row) {
    return ((row & 7) << 1) | ((row >> 3) & 1);
}

// ---------------------------------------------------------------------------
// W conversion -> FRAGMENT-ORDERED bf16x3 tiling, so the GEMM loads each
// B-fragment as ONE lane-contiguous 1 KB global_load_dwordx4 (no LDS at all):
//   wt[kc][ks][nt][p][l] (bf16x8) = plane_p( w[e][k..k+8] ),
//   e = nt*16 + (l&15), k = kc*64 + ks*32 + (l>>4)*8,  l in [0,64).
// Per-lane fragment data is IDENTICAL to r8's verified B mapping.
// ---------------------------------------------------------------------------
__global__ __launch_bounds__(256)
void convert_w_kernel(const float* __restrict__ w, ushort_t* __restrict__ wt)
{
    const int f  = blockIdx.x * 256 + threadIdx.x;   // grid 64x256 = 16384
    const int kc = f >> 9;          // 0..31
    const int ks = (f >> 8) & 1;    // 0..1
    const int nt = (f >> 6) & 3;    // 0..3  (16-expert group)
    const int l  = f & 63;          // lane slot
    const int e  = nt * 16 + (l & 15);
    const int k  = kc * 64 + ks * 32 + (l >> 4) * 8;

    const float* src = w + (size_t)e * HDIM + k;
    const float4 v0 = *(const float4*)(src);
    const float4 v1 = *(const float4*)(src + 4);
    bf16x8 H, M, L;
    split8(v0, v1, H, M, L);

    bf16x8* out = (bf16x8*)wt;
    const int base = (f >> 6) * 3;                    // [kc][ks][nt] row
    out[(size_t)(base + 0) * 64 + l] = H;
    out[(size_t)(base + 1) * 64 + l] = M;
    out[(size_t)(base + 2) * 64 + l] = L;
}

// ---------------------------------------------------------------------------
// FUSED router, round-9: W NEVER touches LDS. B-fragments load directly to
// VGPRs (lane-contiguous 1 KB each from the L2-hot 768 KB pre-tiled planes).
// Only X is LDS-staged (16 KB/block double-buffered) -> per-CU LDS-DMA
// volume drops 2 MB -> 0.5 MB, and 12 of 16 per-wave ds_reads disappear.
//
// Grid 512 x 512 thr (8 waves = a in {0,1} M-tile x b in 0..3 expert-quarter),
// 2 blocks/CU = 16 waves/CU (50%). Per wave-iter: 1 X-DMA instr, 4 ds_read,
// 2 split8, 6 B global loads, 16 MFMA, 1 barrier.
//
// Numerics = r8 exactly: 8 terms in the same order, per-output 4 chains
// (parity x ks) of 128 MFMA-accumulates, same pairwise tree-sum.
// ---------------------------------------------------------------------------
__global__ __launch_bounds__(512, 4)
void router_fused(const float* __restrict__ x,
                  const ushort_t* __restrict__ wt,
                  const float* __restrict__ bias,
                  float* __restrict__ out_scores,
                  float* __restrict__ out_idx)
{
    __shared__ __align__(16) float Xs[2][32 * 64];   // 16 KB

    const int tid  = threadIdx.x;
    const int wv   = tid >> 6;           // 0..7
    const int lane = tid & 63;
    const int t0   = blockIdx.x * 32;
    const int a    = wv >> 2;            // M-tile (16 tokens)
    const int b    = wv & 3;             // expert quarter (16 experts)
    const int lr   = lane & 15;
    const int lg   = lane >> 4;

    const float bv = bias[lane];

    // X staging: wave stages rows wv*4 + (lane>>4); source chunk pre-swizzled
    const int xrow = wv * 4 + (lane >> 4);
    const float* xsrc = x + (size_t)(t0 + xrow) * HDIM
                          + ((lane & 15) ^ xswz(xrow)) * 4;

    // B fragments: wave base; offsets kc*12288 + ks*6144 + p*512 (ushorts)
    const ushort_t* wbp = wt + (size_t)b * 1536 + (size_t)lane * 8;

    f32x4 acc[4];                        // [parity][ks], static indices
#pragma unroll
    for (int i = 0; i < 4; ++i) {
        f32x4 z = {0.0f, 0.0f, 0.0f, 0.0f};
        acc[i] = z;
    }

    const int rowX = a * 16 + lr;
    const int swzX = xswz(rowX);

    auto stage = [&](int kc, int bi) {
        load_lds16(xsrc + kc * 64, &Xs[bi][(wv * 4) * 64]);
    };

#define COMPUTE(BI, PAR, KC) do {                                             \
    const float* rb = &Xs[BI][rowX * 64];                                     \
    _Pragma("unroll")                                                         \
    for (int ks = 0; ks < 2; ++ks) {                                          \
        const int g0 = ks * 8 + lg * 2;                                       \
        const float4 c0 = *(const float4*)(rb + ((g0       ^ swzX) * 4));     \
        const float4 c1 = *(const float4*)(rb + (((g0 + 1) ^ swzX) * 4));     \
        bf16x8 Ah, Am, Al;                                                    \
        split8(c0, c1, Ah, Am, Al);                                           \
        const ushort_t* bb = wbp + (size_t)(KC) * 12288 + ks * 6144;          \
        const bf16x8 Bh = *(const bf16x8*)(bb);                               \
        const bf16x8 Bm = *(const bf16x8*)(bb + 512);                         \
        const bf16x8 Bl = *(const bf16x8*)(bb + 1024);                        \
        f32x4 t = acc[(PAR) * 2 + ks];                                        \
        t = __builtin_amdgcn_mfma_f32_16x16x32_bf16(Ah, Bh, t, 0, 0, 0);      \
        t = __builtin_amdgcn_mfma_f32_16x16x32_bf16(Am, Bh, t, 0, 0, 0);      \
        t = __builtin_amdgcn_mfma_f32_16x16x32_bf16(Ah, Bm, t, 0, 0, 0);      \
        t = __builtin_amdgcn_mfma_f32_16x16x32_bf16(Am, Bm, t, 0, 0, 0);      \
        t = __builtin_amdgcn_mfma_f32_16x16x32_bf16(Al, Bh, t, 0, 0, 0);      \
        t = __builtin_amdgcn_mfma_f32_16x16x32_bf16(Ah, Bl, t, 0, 0, 0);      \
        t = __builtin_amdgcn_mfma_f32_16x16x32_bf16(Al, Bm, t, 0, 0, 0);      \
        t = __builtin_amdgcn_mfma_f32_16x16x32_bf16(Am, Bl, t, 0, 0, 0);      \
        acc[(PAR) * 2 + ks] = t;                                              \
    }                                                                         \
} while (0)

    // ---- prologue ----
    stage(0, 0);
    __syncthreads();

#pragma unroll 1
    for (int j = 0; j < 16; ++j) {
        const int kc0 = j * 2;
        stage(kc0 + 1, 1);
        COMPUTE(0, 0, kc0);
        __syncthreads();                 // drains DMA -> buf1 ready
        if (kc0 + 2 < 32) stage(kc0 + 2, 0);
        COMPUTE(1, 1, kc0 + 1);
        __syncthreads();                 // drains DMA -> buf0 ready
    }
#undef COMPUTE

    // ---- epilogue: tree-sum chains, overlay logits, in-wave top-8 ----
    float* ov = &Xs[0][0];               // 32 tok x 64 exp = 8 KB
    const f32x4 s = (acc[0] + acc[1]) + (acc[2] + acc[3]);
#pragma unroll
    for (int r = 0; r < 4; ++r)
        ov[(a * 16 + lg * 4 + r) * 64 + b * 16 + lr] = s[r];
    __syncthreads();

#pragma unroll 1
    for (int i = 0; i < 4; ++i) {
        const int t = wv * 4 + i;
        const float logit = ov[t * 64 + lane];

        const float score = 1.0f / (1.0f + expf(-logit));
        float key = score + bv;

        float myscore = 0.0f;
        int   myidx   = 0;
        float denom   = 0.0f;

#pragma unroll
        for (int r = 0; r < 8; ++r) {
            float bk = key;
#pragma unroll
            for (int off = 32; off > 0; off >>= 1)
                bk = fmaxf(bk, __shfl_xor(bk, off));
            const unsigned long long msk = __ballot(key == bk);
            const int bi = __ffsll((long long)msk) - 1;   // lowest tied idx
            const float wsc = __shfl(score, bi);          // raw winner score
            denom += wsc;
            if (lane == r)  { myscore = wsc; myidx = bi; }
            if (lane == bi) key = -__builtin_inff();
        }

        const float factor = 2.5f / (denom + 1e-20f);
        if (lane < 8) {
            out_scores[(size_t)(t0 + t) * 8 + lane] = myscore * factor;
            out_idx  [(size_t)(t0 + t) * 8 + lane] = (float)myidx;
        }
    }
}

// ---------------------------------------------------------------------------
// Correctness-only fallback (tiny workspace): naive dot + one-wave topk.
// ---------------------------------------------------------------------------
__global__ void router_gemm_naive(const float* __restrict__ x,
                                  const float* __restrict__ w,
                                  float* __restrict__ partial)
{
    const int t = blockIdx.x;
    const int e = threadIdx.x;          // 64 threads
    const float* xp = x + (size_t)t * HDIM;
    const float* wp = w + (size_t)e * HDIM;
    float s = 0.0f;
    for (int k = 0; k < HDIM; ++k) s = fmaf(xp[k], wp[k], s);
    partial[(size_t)t * NEXP + e] = s;
}

__global__ __launch_bounds__(256)
void router_topk_naive(const float* __restrict__ partial,
                       const float* __restrict__ bias,
                       float* __restrict__ out_scores,
                       float* __restrict__ out_idx)
{
    const int token = blockIdx.x * 4 + (threadIdx.x >> 6);
    const int lane  = threadIdx.x & 63;
    const float logit = partial[(size_t)token * NEXP + lane];
    const float score = 1.0f / (1.0f + expf(-logit));
    float key = score + bias[lane];
    float myscore = 0.0f; int myidx = 0; float denom = 0.0f;
#pragma unroll
    for (int r = 0; r < 8; ++r) {
        float bk = key;
#pragma unroll
        for (int off = 32; off > 0; off >>= 1)
            bk = fmaxf(bk, __shfl_xor(bk, off));
        const unsigned long long msk = __ballot(key == bk);
        const int bi = __ffsll((long long)msk) - 1;
        const float wsc = __shfl(score, bi);
        denom += wsc;
        if (lane == r)  { myscore = wsc; myidx = bi; }
        if (lane == bi) key = -__builtin_inff();
    }
    const float factor = 2.5f / (denom + 1e-20f);
    if (lane < 8) {
        out_scores[(size_t)token * 8 + lane] = myscore * factor;
        out_idx  [(size_t)token * 8 + lane] = (float)myidx;
    }
}

// ---------------------------------------------------------------------------
extern "C" void kernel_launch(void* const* d_in, const int* in_sizes, int n_in,
                              void* d_out, int out_size, void* d_ws, size_t ws_size,
                              hipStream_t stream)
{
    const float* x    = (const float*)d_in[0];   // [4,4096,2048] f32
    const float* bias = (const float*)d_in[1];   // [64] f32
    const float* w    = (const float*)d_in[2];   // [64,2048] f32

    float* out = (float*)d_out;

    const size_t wtBytes = (size_t)3 * NEXP * HDIM * sizeof(ushort_t);  // 768 KB

    if (ws_size >= wtBytes) {
        ushort_t* wt = (ushort_t*)d_ws;
        convert_w_kernel<<<dim3(64), dim3(256), 0, stream>>>(w, wt);
        router_fused<<<dim3(T_TOTAL / 32), dim3(512), 0, stream>>>(
            x, wt, bias, out, out + (size_t)T_TOTAL * 8);
    } else {
        float* partial = (float*)d_ws;           // needs 4 MiB
        router_gemm_naive<<<dim3(T_TOTAL), dim3(64), 0, stream>>>(x, w, partial);
        router_topk_naive<<<dim3(T_TOTAL / 4), dim3(256), 0, stream>>>(
            partial, bias, out, out + (size_t)T_TOTAL * 8);
    }
}